// Round 11
// baseline (5753.175 us; speedup 1.0000x reference)
//
#include <hip/hip_runtime.h>
#include <math.h>

#define TT 256
#define BB 256
#define ID 512
#define HD 512
#define G4 2048            // 4*H
#define KT 1024            // IN + H
#define TBH ((size_t)TT * BB * HD)

typedef short bf16x8 __attribute__((ext_vector_type(8)));
typedef float f32x4  __attribute__((ext_vector_type(4)));
typedef unsigned short u16;
typedef u16  u16x8 __attribute__((ext_vector_type(8)));
typedef u16  u16x4 __attribute__((ext_vector_type(4)));

__device__ __forceinline__ u16 f2b(float f) {
    unsigned u = __builtin_bit_cast(unsigned, f);
    return (u16)((u + 0x7fffu + ((u >> 16) & 1u)) >> 16);   // RNE
}
__device__ __forceinline__ float sigm(float x) { return 1.f / (1.f + __expf(-x)); }
__device__ __forceinline__ float tanh_f(float x) { return 1.f - 2.f / (1.f + __expf(2.f * x)); }

// ===========================================================================
// FAST PATH (needs ~70 MB ws)
// ===========================================================================

// Wfrag: fused-K weights, fragment-sequential per (nb, gate, hc) slice:
//   slice s = (nb*4 + G)*2 + hc   (s in [0,128))
//   Wfrag[((s*32 + kk)*64 + lane)*8 + e], col = G*512 + nb*32 + hc*16 + (lane&15)
//   k = kk*32 + (lane>>4)*8 + e; k<512 -> W_ih[col][k], else W_hh[col][k-512]
__global__ void prep_w(const float* __restrict__ W_ih,
                       const float* __restrict__ W_hh,
                       const float* __restrict__ b_ih,
                       const float* __restrict__ b_hh,
                       u16* __restrict__ Wfrag, float* __restrict__ bc) {
    int idx = blockIdx.x * 256 + threadIdx.x;   // 0 .. 262143 (16B chunks)
    int s  = idx >> 11;
    int kk = (idx >> 6) & 31;
    int l  = idx & 63;
    int nb = s >> 3, G = (s >> 1) & 3, hc = s & 1;
    int col = G * 512 + nb * 32 + hc * 16 + (l & 15);
    int k0  = kk * 32 + (l >> 4) * 8;
    const float* src = (k0 < ID) ? (W_ih + (size_t)col * ID + k0)
                                 : (W_hh + (size_t)col * HD + (k0 - ID));
    u16x8 pk;
    #pragma unroll
    for (int e = 0; e < 8; ++e) pk[e] = f2b(src[e]);
    *reinterpret_cast<u16x8*>(Wfrag + (size_t)idx * 8) = pk;
    if (idx < G4) bc[idx] = b_ih[idx] + b_hh[idx];
}

// feat (f32) -> xb (bf16, row-major) once. 16384 x 256 threads, 8 elems each.
__global__ void prep_x(const float* __restrict__ feat, u16* __restrict__ xb) {
    size_t base = ((size_t)blockIdx.x * 256 + threadIdx.x) * 8;
    const float4* src = reinterpret_cast<const float4*>(feat + base);
    float4 v0 = src[0], v1 = src[1];
    u16x8 pk;
    pk[0]=f2b(v0.x); pk[1]=f2b(v0.y); pk[2]=f2b(v0.z); pk[3]=f2b(v0.w);
    pk[4]=f2b(v1.x); pk[5]=f2b(v1.y); pk[6]=f2b(v1.z); pk[7]=f2b(v1.w);
    *reinterpret_cast<u16x8*>(xb + base) = pk;
}

// Per-step kernel v11 (fused K=1024): 64 blocks x 512 thr.
// bid: xcd=bid&7, mb=(bid>>3)&3, nb=xcd+8*(bid>>5)  -> blocks sharing nb
// (same weights) land on the same XCD for L2 dedup.
// Block: rows [mb*64,+64) x hcols [nb*32,+32) x 4 gates.
// Wave w: wr=w&3 (16-row tile), wg=w>>2 (0: gates i,f; 1: gates g,o).
// 128 MFMAs/wave. Epilogue on the 4 wg0 waves. Kernel boundary = sync.
__launch_bounds__(512, 2)
__global__ void lstm_step(int t,
                          const int* __restrict__ mask,
                          const u16* __restrict__ Wfrag,
                          const u16* __restrict__ xb,
                          const float* __restrict__ bc,
                          const u16* __restrict__ hbp,
                          u16* __restrict__ hbn,
                          float* __restrict__ cb,
                          float* __restrict__ out) {
    __shared__ float exch[4096];            // [wr][g][hc][lane][r] = 16 KB
    const int tid = threadIdx.x;
    const int bid = blockIdx.x;
    const int mb = (bid >> 3) & 3;
    const int nb = (bid & 7) + 8 * (bid >> 5);
    const int w = tid >> 6, lane = tid & 63;
    const int wr = w & 3;
    const int wg = w >> 2;
    const int l15 = lane & 15, l4 = lane >> 4;

    float* hxs0 = out;
    float* hxs1 = out + TBH;
    float* cxs  = out + 2 * TBH;

    const int row_a = mb * 64 + wr * 16 + l15;          // A-fragment row

    const u16* wb[2][2];
    #pragma unroll
    for (int g = 0; g < 2; ++g)
        #pragma unroll
        for (int hc = 0; hc < 2; ++hc)
            wb[g][hc] = Wfrag +
                ((size_t)((nb * 4 + (wg * 2 + g)) * 2 + hc) * 32 * 64) * 8;

    f32x4 acc[2][2] = {};

    // ---- x part: kk 0..15 ----
    const u16* xrow = xb + ((size_t)t * BB + row_a) * ID;
    #pragma unroll
    for (int kk = 0; kk < 16; ++kk) {
        bf16x8 a = *reinterpret_cast<const bf16x8*>(xrow + kk * 32 + l4 * 8);
        #pragma unroll
        for (int g = 0; g < 2; ++g)
            #pragma unroll
            for (int hc = 0; hc < 2; ++hc) {
                bf16x8 b = *reinterpret_cast<const bf16x8*>(
                    wb[g][hc] + (size_t)(kk * 64 + lane) * 8);
                acc[g][hc] = __builtin_amdgcn_mfma_f32_16x16x32_bf16(a, b, acc[g][hc], 0, 0, 0);
            }
    }
    // ---- h part: kk 16..31 (skipped at t=0; state is zero) ----
    if (t > 0) {
        const u16* hrow = hbp + (size_t)row_a * HD;
        #pragma unroll
        for (int kk = 0; kk < 16; ++kk) {
            bf16x8 a = *reinterpret_cast<const bf16x8*>(hrow + kk * 32 + l4 * 8);
            #pragma unroll
            for (int g = 0; g < 2; ++g)
                #pragma unroll
                for (int hc = 0; hc < 2; ++hc) {
                    bf16x8 b = *reinterpret_cast<const bf16x8*>(
                        wb[g][hc] + (size_t)((16 + kk) * 64 + lane) * 8);
                    acc[g][hc] = __builtin_amdgcn_mfma_f32_16x16x32_bf16(a, b, acc[g][hc], 0, 0, 0);
                }
        }
    }

    // ---- wg1 (gates g,o) hands results to wg0 via LDS ----
    if (wg == 1) {
        #pragma unroll
        for (int g = 0; g < 2; ++g)
            #pragma unroll
            for (int hc = 0; hc < 2; ++hc)
                *reinterpret_cast<f32x4*>(
                    &exch[(((wr * 2 + g) * 2 + hc) * 64 + lane) * 4]) = acc[g][hc];
    }
    __syncthreads();

    // ---- pointwise on the 4 wg0 waves ----
    if (wg == 0) {
        const int tm = (t + 1 < TT) ? (t + 1) : (TT - 1);
        int4 mv = *reinterpret_cast<const int4*>(mask + tm * BB + mb * 64 + wr * 16 + l4 * 4);
        #pragma unroll
        for (int hc = 0; hc < 2; ++hc) {
            const int hcol = nb * 32 + hc * 16 + l15;
            float bI = bc[0 * 512 + hcol];
            float bF = bc[1 * 512 + hcol];
            float bG = bc[2 * 512 + hcol];
            float bO = bc[3 * 512 + hcol];
            f32x4 pg = *reinterpret_cast<const f32x4*>(
                &exch[(((wr * 2 + 0) * 2 + hc) * 64 + lane) * 4]);
            f32x4 po = *reinterpret_cast<const f32x4*>(
                &exch[(((wr * 2 + 1) * 2 + hc) * 64 + lane) * 4]);
            #pragma unroll
            for (int r = 0; r < 4; ++r) {
                const int row = mb * 64 + wr * 16 + l4 * 4 + r;
                float cprev = (t > 0) ? cb[(size_t)row * HD + hcol] : 0.f;  // pre-masked
                float kni = 1.f - (float)((&mv.x)[r]);
                float ig = sigm(acc[0][hc][r] + bI);
                float fg = sigm(acc[1][hc][r] + bF);
                float gc = tanh_f(pg[r] + bG);
                float og = sigm(po[r] + bO);
                float c = fg * cprev + ig * gc;
                float h = og * tanh_f(c);

                cb[(size_t)row * HD + hcol] = c * kni;      // pre-masked c

                // pre-masked h (bf16), packed pairwise for 4B stores
                unsigned mine = (unsigned)f2b(h * kni);
                unsigned oth  = (unsigned)__shfl_xor((int)mine, 1, 64);
                if (!(lane & 1)) {
                    unsigned pk = (mine & 0xffffu) | (oth << 16);
                    *reinterpret_cast<unsigned*>(hbn + (size_t)row * HD + hcol) = pk;
                }

                size_t o = ((size_t)t * BB + row) * HD + hcol;
                __builtin_nontemporal_store(h, hxs0 + o);
                __builtin_nontemporal_store(h, hxs1 + o);
                __builtin_nontemporal_store(c, cxs + o);
            }
        }
    }
}

// ===========================================================================
// FALLBACK PATH (round-1, validated): per-step launches, fp32 VALU
// ===========================================================================
__global__ void prep_r1(const float* __restrict__ W_ih, const float* __restrict__ W_hh,
                        const float* __restrict__ b_ih, const float* __restrict__ b_hh,
                        float* __restrict__ WcT, float* __restrict__ bc) {
    int idx = blockIdx.x * 256 + threadIdx.x;
    int k = idx >> 11;
    int j = idx & (G4 - 1);
    float v = (k < ID) ? W_ih[(size_t)j * ID + k] : W_hh[(size_t)j * HD + (k - ID)];
    WcT[idx] = v;
    if (idx < G4) bc[idx] = b_ih[idx] + b_hh[idx];
}

__launch_bounds__(512, 2)
__global__ void lstm_step_r1(int t, int use_ws,
                             const float* __restrict__ feat, const int* __restrict__ mask,
                             const float* __restrict__ W_ih, const float* __restrict__ W_hh,
                             const float* __restrict__ b_ih, const float* __restrict__ b_hh,
                             const float* __restrict__ WcT, const float* __restrict__ bc,
                             float* __restrict__ out) {
    __shared__ float4 xh4[16][256];
    const int tid = threadIdx.x;
    const int c0 = blockIdx.x * 32;
    const int b0 = blockIdx.y * 16;
    float* hxs0 = out;
    float* hxs1 = out + TBH;
    float* cxs  = out + 2 * TBH;

    for (int e = tid; e < 16 * 256; e += 512) {
        int bl = e >> 8, q = e & 255, b = b0 + bl;
        float4 v;
        if (q < 128) {
            v = reinterpret_cast<const float4*>(feat + ((size_t)t * BB + b) * ID)[q];
        } else if (t == 0) {
            v = make_float4(0.f, 0.f, 0.f, 0.f);
        } else {
            float keep = 1.0f - (float)mask[t * BB + b];
            v = reinterpret_cast<const float4*>(hxs0 + ((size_t)(t - 1) * BB + b) * HD)[q - 128];
            v.x *= keep; v.y *= keep; v.z *= keep; v.w *= keep;
        }
        xh4[bl][q] = v;
    }
    __syncthreads();

    const int lc = tid & 127, bh = tid >> 7;
    const int j = (lc >> 5) * HD + c0 + (lc & 31);
    float acc[4] = {0.f, 0.f, 0.f, 0.f};
    if (use_ws) {
        for (int k = 0; k < KT; k += 4) {
            float w0 = WcT[(size_t)(k + 0) * G4 + j];
            float w1 = WcT[(size_t)(k + 1) * G4 + j];
            float w2 = WcT[(size_t)(k + 2) * G4 + j];
            float w3 = WcT[(size_t)(k + 3) * G4 + j];
            #pragma unroll
            for (int i = 0; i < 4; ++i) {
                float4 x = xh4[bh * 4 + i][k >> 2];
                acc[i] = fmaf(x.x, w0, acc[i]); acc[i] = fmaf(x.y, w1, acc[i]);
                acc[i] = fmaf(x.z, w2, acc[i]); acc[i] = fmaf(x.w, w3, acc[i]);
            }
        }
    } else {
        const float4* wi = reinterpret_cast<const float4*>(W_ih + (size_t)j * ID);
        const float4* wh = reinterpret_cast<const float4*>(W_hh + (size_t)j * HD);
        for (int k = 0; k < KT; k += 4) {
            float4 wv = (k < ID) ? wi[k >> 2] : wh[(k - ID) >> 2];
            #pragma unroll
            for (int i = 0; i < 4; ++i) {
                float4 x = xh4[bh * 4 + i][k >> 2];
                acc[i] = fmaf(x.x, wv.x, acc[i]); acc[i] = fmaf(x.y, wv.y, acc[i]);
                acc[i] = fmaf(x.z, wv.z, acc[i]); acc[i] = fmaf(x.w, wv.w, acc[i]);
            }
        }
    }
    float gbias = use_ws ? bc[j] : (b_ih[j] + b_hh[j]);
    __syncthreads();
    float* gbuf = reinterpret_cast<float*>(xh4);
    #pragma unroll
    for (int i = 0; i < 4; ++i) gbuf[lc * 16 + bh * 4 + i] = acc[i] + gbias;
    __syncthreads();
    {
        int hc = tid & 31, bl = tid >> 5, b = b0 + bl;
        float keep = 1.0f - (float)mask[t * BB + b];
        float cp = 0.f;
        if (t > 0) cp = cxs[((size_t)(t - 1) * BB + b) * HD + c0 + hc];
        cp *= keep;
        float ig = gbuf[(0 * 32 + hc) * 16 + bl];
        float fg = gbuf[(1 * 32 + hc) * 16 + bl];
        float gg = gbuf[(2 * 32 + hc) * 16 + bl];
        float og = gbuf[(3 * 32 + hc) * 16 + bl];
        ig = 1.0f / (1.0f + __expf(-ig));
        fg = 1.0f / (1.0f + __expf(-fg));
        gg = tanhf(gg);
        og = 1.0f / (1.0f + __expf(-og));
        float cn = fg * cp + ig * gg;
        float hn = og * tanhf(cn);
        size_t o = ((size_t)t * BB + b) * HD + c0 + hc;
        hxs0[o] = hn; hxs1[o] = hn; cxs[o] = cn;
    }
}

// ===========================================================================
extern "C" void kernel_launch(void* const* d_in, const int* in_sizes, int n_in,
                              void* d_out, int out_size, void* d_ws, size_t ws_size,
                              hipStream_t stream) {
    const float* feat = (const float*)d_in[0];
    const int*   mask = (const int*)d_in[1];
    const float* W_ih = (const float*)d_in[2];
    const float* W_hh = (const float*)d_in[3];
    const float* b_ih = (const float*)d_in[4];
    const float* b_hh = (const float*)d_in[5];
    float* out = (float*)d_out;

    size_t offWf = 0;                                                // 4 MB
    size_t offBc = offWf + (size_t)G4 * KT * sizeof(u16);
    size_t offHb = offBc + (size_t)G4 * sizeof(float);               // +8 KB
    size_t offCb = offHb + (size_t)2 * BB * HD * sizeof(u16);        // +512 KB
    size_t offXb = (offCb + (size_t)BB * HD * sizeof(float) + 255) & ~(size_t)255; // +512 KB
    size_t need  = offXb + (size_t)TT * BB * ID * sizeof(u16);       // +64 MB

    if (d_ws != nullptr && ws_size >= need) {
        char* ws = (char*)d_ws;
        u16*   Wfrag = (u16*)(ws + offWf);
        float* bc    = (float*)(ws + offBc);
        u16*   hb    = (u16*)(ws + offHb);
        float* cb    = (float*)(ws + offCb);
        u16*   xb    = (u16*)(ws + offXb);

        prep_w<<<1024, 256, 0, stream>>>(W_ih, W_hh, b_ih, b_hh, Wfrag, bc);
        prep_x<<<16384, 256, 0, stream>>>(feat, xb);
        for (int t = 0; t < TT; ++t) {
            const u16* hbp = hb + (size_t)(t & 1) * BB * HD;
            u16*       hbn = hb + (size_t)((t + 1) & 1) * BB * HD;
            lstm_step<<<64, 512, 0, stream>>>(t, mask, Wfrag, xb, bc, hbp, hbn, cb, out);
        }
    } else {
        float* WcT = (float*)d_ws;
        float* bcf = WcT + (size_t)KT * G4;
        const size_t ws_needed = ((size_t)KT * G4 + G4) * sizeof(float);
        int use_ws = (d_ws != nullptr && ws_size >= ws_needed) ? 1 : 0;
        if (use_ws)
            prep_r1<<<(KT * G4) / 256, 256, 0, stream>>>(W_ih, W_hh, b_ih, b_hh, WcT, bcf);
        dim3 grid(16, 16);
        for (int t = 0; t < TT; ++t)
            lstm_step_r1<<<grid, 512, 0, stream>>>(t, use_ws, feat, mask,
                                                   W_ih, W_hh, b_ih, b_hh, WcT, bcf, out);
    }
}

// Round 12
// 2379.270 us; speedup vs baseline: 2.4180x; 2.4180x over previous
//
#include <hip/hip_runtime.h>
#include <math.h>

#define TT 256
#define BB 256
#define ID 512
#define HD 512
#define G4 2048            // 4*H
#define KT 1024            // IN + H
#define TBH ((size_t)TT * BB * HD)
#define DMAX 32            // depths handled by dedicated kernels; tail covers rest

typedef short bf16x8 __attribute__((ext_vector_type(8)));
typedef float f32x4  __attribute__((ext_vector_type(4)));
typedef unsigned short u16;
typedef unsigned char  u8;
typedef unsigned int   u32;
typedef u16  u16x8 __attribute__((ext_vector_type(8)));

__device__ __forceinline__ u16 f2b(float f) {
    unsigned u = __builtin_bit_cast(unsigned, f);
    return (u16)((u + 0x7fffu + ((u >> 16) & 1u)) >> 16);   // RNE
}
__device__ __forceinline__ float sigm(float x) { return 1.f / (1.f + __expf(-x)); }
__device__ __forceinline__ float tanh_f(float x) { return 1.f - 2.f / (1.f + __expf(2.f * x)); }

// ===========================================================================
// FAST PATH (needs ~133 MB ws)
// ===========================================================================

// Wfrag: fused-K weights, fragment-sequential per (nb, gate, hc) slice:
//   slice s = (nb*4 + G)*2 + hc, Wfrag[((s*32 + kk)*64 + lane)*8 + e]
//   col = G*512 + nb*32 + hc*16 + (lane&15); k = kk*32 + (lane>>4)*8 + e;
//   k<512 -> W_ih[col][k], else W_hh[col][k-512]. (validated in R11)
__global__ void prep_w(const float* __restrict__ W_ih,
                       const float* __restrict__ W_hh,
                       const float* __restrict__ b_ih,
                       const float* __restrict__ b_hh,
                       u16* __restrict__ Wfrag, float* __restrict__ bc) {
    int idx = blockIdx.x * 256 + threadIdx.x;   // 0 .. 262143 (16B chunks)
    int s  = idx >> 11;
    int kk = (idx >> 6) & 31;
    int l  = idx & 63;
    int nb = s >> 3, G = (s >> 1) & 3, hc = s & 1;
    int col = G * 512 + nb * 32 + hc * 16 + (l & 15);
    int k0  = kk * 32 + (l >> 4) * 8;
    const float* src = (k0 < ID) ? (W_ih + (size_t)col * ID + k0)
                                 : (W_hh + (size_t)col * HD + (k0 - ID));
    u16x8 pk;
    #pragma unroll
    for (int e = 0; e < 8; ++e) pk[e] = f2b(src[e]);
    *reinterpret_cast<u16x8*>(Wfrag + (size_t)idx * 8) = pk;
    if (idx < G4) bc[idx] = b_ih[idx] + b_hh[idx];
}

// feat (f32) -> xb (bf16, row-major) once.
__global__ void prep_x(const float* __restrict__ feat, u16* __restrict__ xb) {
    size_t base = ((size_t)blockIdx.x * 256 + threadIdx.x) * 8;
    const float4* src = reinterpret_cast<const float4*>(feat + base);
    float4 v0 = src[0], v1 = src[1];
    u16x8 pk;
    pk[0]=f2b(v0.x); pk[1]=f2b(v0.y); pk[2]=f2b(v0.z); pk[3]=f2b(v0.w);
    pk[4]=f2b(v1.x); pk[5]=f2b(v1.y); pk[6]=f2b(v1.z); pk[7]=f2b(v1.w);
    *reinterpret_cast<u16x8*>(xb + base) = pk;
}

// Segment bucketing (deterministic, no atomics). 1 block x 256 threads.
// depth d(t,b): 0 if t==0 or mask[t,b]==1, else d(t-1,b)+1.
// entries sorted by (d, b, t): entries[slot] = (t<<8)|b.
__launch_bounds__(256, 1)
__global__ void seg_all(const int* __restrict__ mask,
                        u8*  __restrict__ dmap,
                        u32* __restrict__ counts,
                        u32* __restrict__ offsets,
                        u32* __restrict__ entries) {
    __shared__ u16 c2[256 * 256];   // [d][b] counters -> prefixes -> cursors
    __shared__ u32 aux[256];
    const int tid = threadIdx.x;

    for (int d = 0; d < 256; ++d) c2[d * 256 + tid] = 0;
    __syncthreads();

    // walk1 (tid = b): compute depths, per-(d,b) counts
    {
        int d = 0;
        for (int t = 0; t < 256; ++t) {
            int m = mask[t * 256 + tid];
            d = (t == 0) ? 0 : (m ? 0 : d + 1);
            dmap[t * 256 + tid] = (u8)d;
            c2[d * 256 + tid]++;
        }
    }
    __syncthreads();

    // pass2 (tid = d): exclusive prefix over b within row; row total -> aux
    {
        u32 run = 0;
        for (int b = 0; b < 256; ++b) {
            u32 v = c2[tid * 256 + b];
            c2[tid * 256 + b] = (u16)run;
            run += v;
        }
        aux[tid] = run;
    }
    __syncthreads();

    // serial prefix over depths
    if (tid == 0) {
        u32 run = 0;
        for (int d = 0; d < 256; ++d) {
            u32 v = aux[d];
            counts[d]  = v;
            offsets[d] = run;
            aux[d] = run;
            run += v;
        }
    }
    __syncthreads();

    // pass3 (tid = d): add depth offset -> base cursors (max slot 65535 fits u16)
    {
        u32 o = aux[tid];
        for (int b = 0; b < 256; ++b)
            c2[tid * 256 + b] = (u16)(c2[tid * 256 + b] + o);
    }
    __syncthreads();

    // walk2 (tid = b): scatter entries deterministically
    for (int t = 0; t < 256; ++t) {
        int d = dmap[t * 256 + tid];
        u32 slot = c2[d * 256 + tid]++;
        entries[slot] = (u32)((t << 8) | tid);
    }
}

// One job = 64 gathered rows x one nb slice (32 hcols x 4 gates), K fused.
// 8 waves: wave (wg in [0,4), wh in [0,2)): gate wg, hcols [wh*16,+16).
// A gathered via entries; h-part skipped at depth 0. State: hb16 (bf16 h by
// producer (t,b)), cxs (f32, in d_out). exch = 24KB LDS.
__device__ __forceinline__ void depth_job(
    int s, int j, int gcnt, int goff,
    const u32* __restrict__ entries,
    const u16* __restrict__ Wfrag,
    const u16* __restrict__ xb,
    u16* __restrict__ hb16,
    const float* __restrict__ bc,
    float* __restrict__ out,
    float* exch, int tid)
{
    const int w = tid >> 6, lane = tid & 63;
    const int wg = w >> 1, wh = w & 1;
    const int l15 = lane & 15, l4 = lane >> 4;
    const int nb = j & 15, jt = j >> 4;

    float* hxs0 = out;
    float* hxs1 = out + TBH;
    float* cxs  = out + 2 * TBH;

    // A row bases for the 4 row-fragments (clamped for padding)
    const u16* xa[4];
    const u16* ha[4];
    #pragma unroll
    for (int fr = 0; fr < 4; ++fr) {
        int i = jt * 64 + fr * 16 + l15;
        if (i >= gcnt) i = gcnt - 1;
        u32 ee = entries[goff + i];               // ee == t*256 + b
        xa[fr] = xb   + (size_t)ee * ID;
        ha[fr] = hb16 + (size_t)(ee - 256) * HD;  // (t-1,b); valid when s>0
    }

    const u16* wb = Wfrag + (size_t)((nb * 4 + wg) * 2 + wh) * (32 * 64 * 8);

    f32x4 acc[4] = {};
    #pragma unroll
    for (int kk = 0; kk < 16; ++kk) {             // x part (k 0..511)
        bf16x8 bf = *reinterpret_cast<const bf16x8*>(wb + (size_t)(kk * 64 + lane) * 8);
        #pragma unroll
        for (int fr = 0; fr < 4; ++fr) {
            bf16x8 a = *reinterpret_cast<const bf16x8*>(xa[fr] + kk * 32 + l4 * 8);
            acc[fr] = __builtin_amdgcn_mfma_f32_16x16x32_bf16(a, bf, acc[fr], 0, 0, 0);
        }
    }
    if (s > 0) {                                   // h part (k 512..1023)
        #pragma unroll
        for (int kk = 0; kk < 16; ++kk) {
            bf16x8 bf = *reinterpret_cast<const bf16x8*>(wb + (size_t)((16 + kk) * 64 + lane) * 8);
            #pragma unroll
            for (int fr = 0; fr < 4; ++fr) {
                bf16x8 a = *reinterpret_cast<const bf16x8*>(ha[fr] + kk * 32 + l4 * 8);
                acc[fr] = __builtin_amdgcn_mfma_f32_16x16x32_bf16(a, bf, acc[fr], 0, 0, 0);
            }
        }
    }

    if (wg >= 1) {
        #pragma unroll
        for (int fr = 0; fr < 4; ++fr)
            *reinterpret_cast<f32x4*>(
                &exch[((((wg - 1) * 2 + wh) * 4 + fr) * 64 + lane) * 4]) = acc[fr];
    }
    __syncthreads();

    if (wg == 0) {
        const int hcol = nb * 32 + wh * 16 + l15;
        const float bI = bc[hcol], bF = bc[512 + hcol];
        const float bG = bc[1024 + hcol], bO = bc[1536 + hcol];
        #pragma unroll
        for (int fr = 0; fr < 4; ++fr) {
            f32x4 pf = *reinterpret_cast<const f32x4*>(&exch[(((0 * 2 + wh) * 4 + fr) * 64 + lane) * 4]);
            f32x4 pg = *reinterpret_cast<const f32x4*>(&exch[(((1 * 2 + wh) * 4 + fr) * 64 + lane) * 4]);
            f32x4 po = *reinterpret_cast<const f32x4*>(&exch[(((2 * 2 + wh) * 4 + fr) * 64 + lane) * 4]);
            #pragma unroll
            for (int r = 0; r < 4; ++r) {
                int i = jt * 64 + fr * 16 + l4 * 4 + r;
                if (i < gcnt) {
                    u32 ee = entries[goff + i];
                    float cprev = (s > 0) ? cxs[(size_t)(ee - 256) * HD + hcol] : 0.f;
                    float ig = sigm(acc[fr][r] + bI);
                    float fg = sigm(pf[r] + bF);
                    float gc = tanh_f(pg[r] + bG);
                    float og = sigm(po[r] + bO);
                    float c = fg * cprev + ig * gc;
                    float h = og * tanh_f(c);
                    size_t o = (size_t)ee * HD + hcol;
                    __builtin_nontemporal_store(h, hxs0 + o);
                    __builtin_nontemporal_store(h, hxs1 + o);
                    cxs[o]  = c;            // read by next depth
                    hb16[o] = f2b(h);       // read by next depth
                }
            }
        }
    }
    __syncthreads();
}

__launch_bounds__(512, 2)
__global__ void lstm_depth(int s,
                           const u32* __restrict__ counts,
                           const u32* __restrict__ offsets,
                           const u32* __restrict__ entries,
                           const u16* __restrict__ Wfrag,
                           const u16* __restrict__ xb,
                           u16* __restrict__ hb16,
                           const float* __restrict__ bc,
                           float* __restrict__ out) {
    __shared__ float exch[6144];   // 24 KB
    int gcnt = counts[s];
    if (gcnt == 0) return;
    int goff = offsets[s];
    int njobs = ((gcnt + 63) >> 6) << 4;
    // stride 256 keeps nb = j&15 constant per block -> weights L1-resident
    for (int j = blockIdx.x; j < njobs; j += 256)
        depth_job(s, j, gcnt, goff, entries, Wfrag, xb, hb16, bc, out,
                  exch, threadIdx.x);
}

// Tail: correctness backstop for depths >= DMAX (expected zero work for
// Bernoulli masks). Single block; within-block fence between depths.
__launch_bounds__(512, 1)
__global__ void lstm_tail(const u32* __restrict__ counts,
                          const u32* __restrict__ offsets,
                          const u32* __restrict__ entries,
                          const u16* __restrict__ Wfrag,
                          const u16* __restrict__ xb,
                          u16* __restrict__ hb16,
                          const float* __restrict__ bc,
                          float* __restrict__ out) {
    __shared__ float exch[6144];
    for (int s = DMAX; s < 256; ++s) {
        int gcnt = counts[s];
        if (gcnt == 0) continue;
        int goff = offsets[s];
        int njobs = ((gcnt + 63) >> 6) << 4;
        for (int j = 0; j < njobs; ++j)
            depth_job(s, j, gcnt, goff, entries, Wfrag, xb, hb16, bc, out,
                      exch, threadIdx.x);
        __threadfence();
        __syncthreads();
    }
}

// ===========================================================================
// FALLBACK PATH (round-1, validated): per-step launches, fp32 VALU
// ===========================================================================
__global__ void prep_r1(const float* __restrict__ W_ih, const float* __restrict__ W_hh,
                        const float* __restrict__ b_ih, const float* __restrict__ b_hh,
                        float* __restrict__ WcT, float* __restrict__ bc) {
    int idx = blockIdx.x * 256 + threadIdx.x;
    int k = idx >> 11;
    int j = idx & (G4 - 1);
    float v = (k < ID) ? W_ih[(size_t)j * ID + k] : W_hh[(size_t)j * HD + (k - ID)];
    WcT[idx] = v;
    if (idx < G4) bc[idx] = b_ih[idx] + b_hh[idx];
}

__launch_bounds__(512, 2)
__global__ void lstm_step_r1(int t, int use_ws,
                             const float* __restrict__ feat, const int* __restrict__ mask,
                             const float* __restrict__ W_ih, const float* __restrict__ W_hh,
                             const float* __restrict__ b_ih, const float* __restrict__ b_hh,
                             const float* __restrict__ WcT, const float* __restrict__ bc,
                             float* __restrict__ out) {
    __shared__ float4 xh4[16][256];
    const int tid = threadIdx.x;
    const int c0 = blockIdx.x * 32;
    const int b0 = blockIdx.y * 16;
    float* hxs0 = out;
    float* hxs1 = out + TBH;
    float* cxs  = out + 2 * TBH;

    for (int e = tid; e < 16 * 256; e += 512) {
        int bl = e >> 8, q = e & 255, b = b0 + bl;
        float4 v;
        if (q < 128) {
            v = reinterpret_cast<const float4*>(feat + ((size_t)t * BB + b) * ID)[q];
        } else if (t == 0) {
            v = make_float4(0.f, 0.f, 0.f, 0.f);
        } else {
            float keep = 1.0f - (float)mask[t * BB + b];
            v = reinterpret_cast<const float4*>(hxs0 + ((size_t)(t - 1) * BB + b) * HD)[q - 128];
            v.x *= keep; v.y *= keep; v.z *= keep; v.w *= keep;
        }
        xh4[bl][q] = v;
    }
    __syncthreads();

    const int lc = tid & 127, bh = tid >> 7;
    const int j = (lc >> 5) * HD + c0 + (lc & 31);
    float acc[4] = {0.f, 0.f, 0.f, 0.f};
    if (use_ws) {
        for (int k = 0; k < KT; k += 4) {
            float w0 = WcT[(size_t)(k + 0) * G4 + j];
            float w1 = WcT[(size_t)(k + 1) * G4 + j];
            float w2 = WcT[(size_t)(k + 2) * G4 + j];
            float w3 = WcT[(size_t)(k + 3) * G4 + j];
            #pragma unroll
            for (int i = 0; i < 4; ++i) {
                float4 x = xh4[bh * 4 + i][k >> 2];
                acc[i] = fmaf(x.x, w0, acc[i]); acc[i] = fmaf(x.y, w1, acc[i]);
                acc[i] = fmaf(x.z, w2, acc[i]); acc[i] = fmaf(x.w, w3, acc[i]);
            }
        }
    } else {
        const float4* wi = reinterpret_cast<const float4*>(W_ih + (size_t)j * ID);
        const float4* wh = reinterpret_cast<const float4*>(W_hh + (size_t)j * HD);
        for (int k = 0; k < KT; k += 4) {
            float4 wv = (k < ID) ? wi[k >> 2] : wh[(k - ID) >> 2];
            #pragma unroll
            for (int i = 0; i < 4; ++i) {
                float4 x = xh4[bh * 4 + i][k >> 2];
                acc[i] = fmaf(x.x, wv.x, acc[i]); acc[i] = fmaf(x.y, wv.y, acc[i]);
                acc[i] = fmaf(x.z, wv.z, acc[i]); acc[i] = fmaf(x.w, wv.w, acc[i]);
            }
        }
    }
    float gbias = use_ws ? bc[j] : (b_ih[j] + b_hh[j]);
    __syncthreads();
    float* gbuf = reinterpret_cast<float*>(xh4);
    #pragma unroll
    for (int i = 0; i < 4; ++i) gbuf[lc * 16 + bh * 4 + i] = acc[i] + gbias;
    __syncthreads();
    {
        int hc = tid & 31, bl = tid >> 5, b = b0 + bl;
        float keep = 1.0f - (float)mask[t * BB + b];
        float cp = 0.f;
        if (t > 0) cp = cxs[((size_t)(t - 1) * BB + b) * HD + c0 + hc];
        cp *= keep;
        float ig = gbuf[(0 * 32 + hc) * 16 + bl];
        float fg = gbuf[(1 * 32 + hc) * 16 + bl];
        float gg = gbuf[(2 * 32 + hc) * 16 + bl];
        float og = gbuf[(3 * 32 + hc) * 16 + bl];
        ig = 1.0f / (1.0f + __expf(-ig));
        fg = 1.0f / (1.0f + __expf(-fg));
        gg = tanhf(gg);
        og = 1.0f / (1.0f + __expf(-og));
        float cn = fg * cp + ig * gg;
        float hn = og * tanhf(cn);
        size_t o = ((size_t)t * BB + b) * HD + c0 + hc;
        hxs0[o] = hn; hxs1[o] = hn; cxs[o] = cn;
    }
}

// ===========================================================================
extern "C" void kernel_launch(void* const* d_in, const int* in_sizes, int n_in,
                              void* d_out, int out_size, void* d_ws, size_t ws_size,
                              hipStream_t stream) {
    const float* feat = (const float*)d_in[0];
    const int*   mask = (const int*)d_in[1];
    const float* W_ih = (const float*)d_in[2];
    const float* W_hh = (const float*)d_in[3];
    const float* b_ih = (const float*)d_in[4];
    const float* b_hh = (const float*)d_in[5];
    float* out = (float*)d_out;

    size_t offWf  = 0;                                               // 4 MB
    size_t offBc  = offWf  + (size_t)G4 * KT * sizeof(u16);
    size_t offXb  = offBc  + (size_t)G4 * sizeof(float);             // +8 KB
    size_t offHb  = offXb  + (size_t)TT * BB * ID * sizeof(u16);     // +64 MB
    size_t offDm  = offHb  + (size_t)TT * BB * HD * sizeof(u16);     // +64 MB
    size_t offCnt = offDm  + (size_t)TT * BB;                        // +64 KB
    size_t offOff = offCnt + 1024;
    size_t offEnt = offOff + 1024;
    size_t need   = offEnt + ((size_t)TT * BB + 256) * sizeof(u32);  // +~257 KB

    if (d_ws != nullptr && ws_size >= need) {
        char* ws = (char*)d_ws;
        u16*   Wfrag = (u16*)(ws + offWf);
        float* bc    = (float*)(ws + offBc);
        u16*   xb    = (u16*)(ws + offXb);
        u16*   hb16  = (u16*)(ws + offHb);
        u8*    dmap  = (u8*)(ws + offDm);
        u32*   counts  = (u32*)(ws + offCnt);
        u32*   offsets = (u32*)(ws + offOff);
        u32*   entries = (u32*)(ws + offEnt);

        prep_w<<<1024, 256, 0, stream>>>(W_ih, W_hh, b_ih, b_hh, Wfrag, bc);
        prep_x<<<16384, 256, 0, stream>>>(feat, xb);
        seg_all<<<1, 256, 0, stream>>>(mask, dmap, counts, offsets, entries);
        for (int s = 0; s < DMAX; ++s)
            lstm_depth<<<256, 512, 0, stream>>>(s, counts, offsets, entries,
                                                Wfrag, xb, hb16, bc, out);
        lstm_tail<<<1, 512, 0, stream>>>(counts, offsets, entries,
                                         Wfrag, xb, hb16, bc, out);
    } else {
        float* WcT = (float*)d_ws;
        float* bcf = WcT + (size_t)KT * G4;
        const size_t ws_needed = ((size_t)KT * G4 + G4) * sizeof(float);
        int use_ws = (d_ws != nullptr && ws_size >= ws_needed) ? 1 : 0;
        if (use_ws)
            prep_r1<<<(KT * G4) / 256, 256, 0, stream>>>(W_ih, W_hh, b_ih, b_hh, WcT, bcf);
        dim3 grid(16, 16);
        for (int t = 0; t < TT; ++t)
            lstm_step_r1<<<grid, 512, 0, stream>>>(t, use_ws, feat, mask,
                                                   W_ih, W_hh, b_ih, b_hh, WcT, bcf, out);
    }
}